// Round 7
// baseline (6158.904 us; speedup 1.0000x reference)
//
#include <hip/hip_runtime.h>
#include <hip/hip_bf16.h>
#include <math.h>

typedef __hip_bfloat16 bf16;
typedef __bf16 v8bf __attribute__((ext_vector_type(8)));
typedef float v4f __attribute__((ext_vector_type(4)));
typedef unsigned long long ull;

#define BN_SCALE 0.9999950000374997f
#define NPTS 1024
#define NB 4
#define TW 40  // LDS tile row stride in bf16 (80B: 2-way bank alias only = free)

__device__ __forceinline__ float b2f(bf16 v) { return __bfloat162float(v); }
__device__ __forceinline__ bf16 f2b(float v) { return __float2bfloat16(v); }
// dtype-flag-aware load: isf=1 -> fp32 data, isf=0 -> bf16 data
__device__ __forceinline__ float ldw(const void* p, size_t i, int isf) {
    return isf ? ((const float*)p)[i] : b2f(((const bf16*)p)[i]);
}
// order-preserving float<->uint transform (monotone increasing)
__device__ __forceinline__ unsigned ordf(float f) {
    unsigned u = __float_as_uint(f);
    return (u & 0x80000000u) ? ~u : (u | 0x80000000u);
}
__device__ __forceinline__ float iordf(unsigned u) {
    return (u & 0x80000000u) ? __uint_as_float(u ^ 0x80000000u) : __uint_as_float(~u);
}

// ---------------- dtype probe (fp32=1 / bf16=0) + pooled init ----------------
__global__ void k_probe(const void* xraw, int* flag, unsigned* pooledU) {
    __shared__ int cnt[256];
    const unsigned short* u = (const unsigned short*)xraw;
    int t = threadIdx.x, c = 0;
    for (int i = t; i < 8192; i += 256) {
        unsigned short v = u[i];
        int e = (v >> 7) & 0xFF;
        int m = v & 0x7F;
        if (e == 0xFF || e >= 141 || (e == 0 && m != 0)) c++;
    }
    cnt[t] = c;
    for (int i = t; i < 2048; i += 256) pooledU[i] = 0u;  // 0 < ordf(any finite)
    __syncthreads();
    for (int off = 128; off > 0; off >>= 1) {
        if (t < off) cnt[t] += cnt[t + off];
        __syncthreads();
    }
    if (t == 0) *flag = (cnt[0] > 200) ? 1 : 0;
}

// fill a 64x32 bf16 tile (rows stride ld) into LDS [64][TW]; 256 threads x 16B
__device__ __forceinline__ void fillA(bf16* dst, const bf16* srcRowBase, int ld) {
    int t = threadIdx.x; int r = t >> 2; int kq = (t & 3) << 3;
    *(float4*)(dst + r * TW + kq) = *(const float4*)(srcRowBase + (size_t)r * ld + kq);
}
// MFMA fragment: sub-tile 'sub' (16 rows), lane l: row=sub*16+(l&15), k=(l>>4)*8
__device__ __forceinline__ v8bf ldfrag(const bf16* tile, int sub, int l) {
    return *(const v8bf*)(tile + (size_t)(sub * 16 + (l & 15)) * TW + ((l >> 4) << 3));
}

// ---------------- layer-1 prep: pad x to 32 cols as hi/lo bf16 split + sq ----------------
__global__ void k_xpad(const void* __restrict__ x, int base, const int* __restrict__ flag,
                       bf16* __restrict__ xph, bf16* __restrict__ xpl, float* __restrict__ sq) {
    int isf = *flag;
    int n = blockIdx.x * 256 + threadIdx.x;
    if (n >= NPTS) return;
    float s = 0.f;
    for (int c = 0; c < 32; c++) {
        float v = (c < 3) ? ldw(x, (size_t)base + n * 3 + c, isf) : 0.f;
        bf16 h = f2b(v);
        xph[n * 32 + c] = h;
        xpl[n * 32 + c] = f2b(v - b2f(h));
        s += v * v;
    }
    sq[n] = s;
}

// top-k sorted-ascending LDS list insert; key = (ordf(v)<<32)|~idx
// evictee = L[0]; uniform rule, order-independent, replicates jax (v desc, idx asc)
__device__ __forceinline__ void tk_insert(ull* L, ull kk) {
    if (kk > L[0]) {
        int j = 1;
        while (j < 20 && L[j] < kk) { L[j - 1] = L[j]; j++; }
        L[j - 1] = kk;
    }
}

// ---------------- FUSED dist + top-20: 16 query rows per block, D never materialized ----------------
__global__ __launch_bounds__(256) void k_distk(const bf16* __restrict__ Xhi, const bf16* __restrict__ Xlo,
                                               int ld, int Kpad, const float* __restrict__ sqg,
                                               int* __restrict__ idx) {
    __shared__ float sqs[NPTS];
    __shared__ alignas(16) bf16 Ah[2][16 * TW], Al[2][16 * TW];
    __shared__ alignas(16) bf16 Bh[2][128 * TW], Bl[2][128 * TW];
    __shared__ float Dt[16][137];
    __shared__ ull lst[2][16][20];
    int t = threadIdx.x;
    int n0 = blockIdx.x * 16;
    for (int i = t; i < NPTS; i += 256) sqs[i] = sqg[i];
    if (t < 32) {
        ull* L = lst[t >> 4][t & 15];
        for (int s = 0; s < 20; s++) L[s] = 0ull;
    }
    int w = t >> 6, l = t & 63;
    int quad = l >> 4, col = l & 15;
    int nk = Kpad >> 5;
    int ar = t >> 2, ac = (t & 3) << 3;  // A staging (threads 0..63)
    int br = t >> 2, bc = (t & 3) << 3;  // B staging (rows br, br+64)

    for (int mc = 0; mc < 8; mc++) {
        int m0 = mc * 128;
        // preload k0=0 into buffer 0
        if (t < 64) {
            *(float4*)&Ah[0][ar * TW + ac] = *(const float4*)(Xhi + (size_t)(n0 + ar) * ld + ac);
            *(float4*)&Al[0][ar * TW + ac] = *(const float4*)(Xlo + (size_t)(n0 + ar) * ld + ac);
        }
        *(float4*)&Bh[0][br * TW + bc]        = *(const float4*)(Xhi + (size_t)(m0 + br) * ld + bc);
        *(float4*)&Bh[0][(br + 64) * TW + bc] = *(const float4*)(Xhi + (size_t)(m0 + br + 64) * ld + bc);
        *(float4*)&Bl[0][br * TW + bc]        = *(const float4*)(Xlo + (size_t)(m0 + br) * ld + bc);
        *(float4*)&Bl[0][(br + 64) * TW + bc] = *(const float4*)(Xlo + (size_t)(m0 + br + 64) * ld + bc);
        __syncthreads();
        v4f acc0 = {0.f, 0.f, 0.f, 0.f}, acc1 = {0.f, 0.f, 0.f, 0.f};
        for (int ki = 0; ki < nk; ki++) {
            int bb = ki & 1;
            if (ki + 1 < nk) {  // stage next k-window into other buffer (no extra barrier)
                int k0 = (ki + 1) << 5;
                int nb2 = bb ^ 1;
                if (t < 64) {
                    *(float4*)&Ah[nb2][ar * TW + ac] = *(const float4*)(Xhi + (size_t)(n0 + ar) * ld + k0 + ac);
                    *(float4*)&Al[nb2][ar * TW + ac] = *(const float4*)(Xlo + (size_t)(n0 + ar) * ld + k0 + ac);
                }
                *(float4*)&Bh[nb2][br * TW + bc]        = *(const float4*)(Xhi + (size_t)(m0 + br) * ld + k0 + bc);
                *(float4*)&Bh[nb2][(br + 64) * TW + bc] = *(const float4*)(Xhi + (size_t)(m0 + br + 64) * ld + k0 + bc);
                *(float4*)&Bl[nb2][br * TW + bc]        = *(const float4*)(Xlo + (size_t)(m0 + br) * ld + k0 + bc);
                *(float4*)&Bl[nb2][(br + 64) * TW + bc] = *(const float4*)(Xlo + (size_t)(m0 + br + 64) * ld + k0 + bc);
            }
            v8bf ah = *(const v8bf*)&Ah[bb][(l & 15) * TW + quad * 8];
            v8bf al = *(const v8bf*)&Al[bb][(l & 15) * TW + quad * 8];
            int brow = w * 16 + (l & 15);
            v8bf bh0 = *(const v8bf*)&Bh[bb][brow * TW + quad * 8];
            v8bf bl0 = *(const v8bf*)&Bl[bb][brow * TW + quad * 8];
            v8bf bh1 = *(const v8bf*)&Bh[bb][(brow + 64) * TW + quad * 8];
            v8bf bl1 = *(const v8bf*)&Bl[bb][(brow + 64) * TW + quad * 8];
            acc0 = __builtin_amdgcn_mfma_f32_16x16x32_bf16(ah, bh0, acc0, 0, 0, 0);
            acc0 = __builtin_amdgcn_mfma_f32_16x16x32_bf16(ah, bl0, acc0, 0, 0, 0);
            acc0 = __builtin_amdgcn_mfma_f32_16x16x32_bf16(al, bh0, acc0, 0, 0, 0);
            acc1 = __builtin_amdgcn_mfma_f32_16x16x32_bf16(ah, bh1, acc1, 0, 0, 0);
            acc1 = __builtin_amdgcn_mfma_f32_16x16x32_bf16(ah, bl1, acc1, 0, 0, 0);
            acc1 = __builtin_amdgcn_mfma_f32_16x16x32_bf16(al, bh1, acc1, 0, 0, 0);
            __syncthreads();
        }
        int nloc = quad * 4;
#pragma unroll
        for (int r = 0; r < 4; r++) {
            float sn = sqs[n0 + nloc + r];
            Dt[nloc + r][w * 16 + col]      = 2.f * acc0[r] - sn - sqs[m0 + w * 16 + col];
            Dt[nloc + r][64 + w * 16 + col] = 2.f * acc1[r] - sn - sqs[m0 + 64 + w * 16 + col];
        }
        __syncthreads();
        if (t < 32) {
            int sl = t >> 4, row = t & 15;
            ull* L = lst[sl][row];
            int cbase = sl * 64;
            for (int c = 0; c < 64; c++) {
                float d = Dt[row][cbase + c];
                unsigned m = (unsigned)(m0 + cbase + c);
                ull kk = ((ull)ordf(d) << 32) | (ull)(~m);
                tk_insert(L, kk);
            }
        }
        __syncthreads();
    }
    if (t < 16) {
        ull* L0 = lst[0][t];
        for (int s = 0; s < 20; s++) tk_insert(L0, lst[1][t][s]);
        for (int s = 0; s < 20; s++)
            idx[(n0 + t) * 20 + s] = (int)(~(unsigned)(L0[s] & 0xFFFFFFFFull));
    }
}

// ---------------- st via MFMA: P[m][0:O)=Wa.x, P[m][O:2O)=Wb.x (W dtype per flag) ----------------
__global__ __launch_bounds__(256) void k_st(const bf16* __restrict__ Xhi, const bf16* __restrict__ Xlo,
                                            int ld, int C, int Kpad,
                                            const void* __restrict__ W, int O, float* __restrict__ P,
                                            const int* __restrict__ flag) {
    __shared__ alignas(16) bf16 Ah[64 * TW], Al[64 * TW], Bh[64 * TW], Bl[64 * TW];
    int isf = *flag;
    int m0 = blockIdx.y * 64, n0 = blockIdx.x * 64;
    int N2 = 2 * O;
    int w = threadIdx.x >> 6, l = threadIdx.x & 63;
    v4f zero = {0.f, 0.f, 0.f, 0.f};
    v4f acc[4] = {zero, zero, zero, zero};
    for (int k0 = 0; k0 < Kpad; k0 += 32) {
        __syncthreads();
        fillA(Ah, Xhi + (size_t)m0 * ld + k0, ld);
        fillA(Al, Xlo + (size_t)m0 * ld + k0, ld);
        {
            int t = threadIdx.x; int r = t >> 2; int kq = (t & 3) << 3;
            int n = n0 + r;
            size_t rowoff = (n < O) ? (size_t)n * 2 * C : (size_t)(n - O) * 2 * C + C;
            for (int j = 0; j < 8; j++) {
                int c = k0 + kq + j;
                float wv = (c < C) ? ldw(W, rowoff + c, isf) : 0.f;
                bf16 h = f2b(wv);
                Bh[r * TW + kq + j] = h;
                Bl[r * TW + kq + j] = f2b(wv - b2f(h));
            }
        }
        __syncthreads();
        v8bf ah = ldfrag(Ah, w, l);
        v8bf al = ldfrag(Al, w, l);
#pragma unroll
        for (int nt = 0; nt < 4; nt++) {
            v8bf bh = ldfrag(Bh, nt, l);
            v8bf bl = ldfrag(Bl, nt, l);
            acc[nt] = __builtin_amdgcn_mfma_f32_16x16x32_bf16(ah, bh, acc[nt], 0, 0, 0);
            acc[nt] = __builtin_amdgcn_mfma_f32_16x16x32_bf16(ah, bl, acc[nt], 0, 0, 0);
            acc[nt] = __builtin_amdgcn_mfma_f32_16x16x32_bf16(al, bh, acc[nt], 0, 0, 0);
        }
    }
    int quad = l >> 4, col = l & 15;
    int rb = m0 + 16 * w + quad * 4;
#pragma unroll
    for (int r = 0; r < 4; r++)
#pragma unroll
        for (int nt = 0; nt < 4; nt++)
            P[(size_t)(rb + r) * N2 + n0 + nt * 16 + col] = acc[nt][r];
}

// ---------------- conv5 via MFMA + fused affine/lrelu/max-pool via atomicMax ----------------
__global__ __launch_bounds__(256) void k_conv5(const bf16* __restrict__ Xhi, const bf16* __restrict__ Xlo,
                                               const void* __restrict__ W,
                                               const void* __restrict__ g, const void* __restrict__ bias,
                                               unsigned* __restrict__ pooledU, int b,
                                               const int* __restrict__ flag) {
    __shared__ alignas(16) bf16 Ah[64 * TW], Al[64 * TW], Bh[64 * TW], Bl[64 * TW];
    __shared__ float red[4][4][16];
    int isf = *flag;
    int m0 = blockIdx.y * 64, o0 = blockIdx.x * 64;
    int w = threadIdx.x >> 6, l = threadIdx.x & 63;
    v4f zero = {0.f, 0.f, 0.f, 0.f};
    v4f acc[4] = {zero, zero, zero, zero};
    for (int k0 = 0; k0 < 960; k0 += 32) {
        __syncthreads();
        fillA(Ah, Xhi + (size_t)m0 * 960 + k0, 960);
        fillA(Al, Xlo + (size_t)m0 * 960 + k0, 960);
        {
            int t = threadIdx.x; int r = t >> 2; int kq = (t & 3) << 3;
            size_t rowoff = (size_t)(o0 + r) * 960;
            for (int j = 0; j < 8; j++) {
                float wv = ldw(W, rowoff + k0 + kq + j, isf);
                bf16 h = f2b(wv);
                Bh[r * TW + kq + j] = h;
                Bl[r * TW + kq + j] = f2b(wv - b2f(h));
            }
        }
        __syncthreads();
        v8bf ah = ldfrag(Ah, w, l);
        v8bf al = ldfrag(Al, w, l);
#pragma unroll
        for (int nt = 0; nt < 4; nt++) {
            v8bf bh = ldfrag(Bh, nt, l);
            v8bf bl = ldfrag(Bl, nt, l);
            acc[nt] = __builtin_amdgcn_mfma_f32_16x16x32_bf16(ah, bh, acc[nt], 0, 0, 0);
            acc[nt] = __builtin_amdgcn_mfma_f32_16x16x32_bf16(ah, bl, acc[nt], 0, 0, 0);
            acc[nt] = __builtin_amdgcn_mfma_f32_16x16x32_bf16(al, bh, acc[nt], 0, 0, 0);
        }
    }
    int quad = l >> 4, col = l & 15;
#pragma unroll
    for (int nt = 0; nt < 4; nt++) {
        int o = o0 + nt * 16 + col;
        float scl = ldw(g, o, isf) * BN_SCALE;
        float bi = ldw(bias, o, isf);
        float ym = -__builtin_inff();
#pragma unroll
        for (int r = 0; r < 4; r++) {
            float v = acc[nt][r] * scl + bi;
            v = v > 0.f ? v : 0.2f * v;
            ym = fmaxf(ym, v);
        }
        ym = fmaxf(ym, __shfl_down(ym, 32));
        ym = fmaxf(ym, __shfl_down(ym, 16));
        if (quad == 0) red[w][nt][col] = ym;
    }
    __syncthreads();
    if (threadIdx.x < 64) {
        int nt = threadIdx.x >> 4, c = threadIdx.x & 15;
        float m = fmaxf(fmaxf(red[0][nt][c], red[1][nt][c]), fmaxf(red[2][nt][c], red[3][nt][c]));
        atomicMax(&pooledU[b * 512 + o0 + nt * 16 + c], ordf(m));
    }
}

// ---------------- gather + affine + lrelu + max over k -> xc hi/lo; fused sq ----------------
__global__ void k_gmax(const float* __restrict__ P, const int* __restrict__ idx,
                       const void* __restrict__ g, const void* __restrict__ bias, int O,
                       bf16* __restrict__ xhOut, bf16* __restrict__ xlOut,
                       float* __restrict__ sqOut, int writeSq, const int* __restrict__ flag) {
    __shared__ int id[20];
    __shared__ float red[8];
    int isf = *flag;
    int n = blockIdx.x;
    int o = threadIdx.x;  // blockDim.x == O
    if (o < 20) id[o] = idx[n * 20 + o];
    __syncthreads();
    int N2 = 2 * O;
    float tv = P[(size_t)n * N2 + O + o] - P[(size_t)n * N2 + o];
    float scl = ldw(g, o, isf) * BN_SCALE;
    float bi = ldw(bias, o, isf);
    float acc = -__builtin_inff();
    for (int j = 0; j < 20; j++) {
        int m = id[j];
        float v = P[(size_t)m * N2 + o] + tv;
        float z = v * scl + bi;
        z = z > 0.f ? z : 0.2f * z;
        acc = fmaxf(acc, z);
    }
    bf16 hi = f2b(acc);
    bf16 lo = f2b(acc - b2f(hi));
    xhOut[(size_t)n * 960 + o] = hi;
    xlOut[(size_t)n * 960 + o] = lo;
    if (writeSq) {
        float xv = b2f(hi) + b2f(lo);
        float s = xv * xv;
#pragma unroll
        for (int off = 32; off > 0; off >>= 1) s += __shfl_down(s, off);
        if ((o & 63) == 0) red[o >> 6] = s;
        __syncthreads();
        if (o == 0) {
            float tot = 0.f;
            for (int i = 0; i < (O >> 6); i++) tot += red[i];
            sqOut[n] = tot;
        }
    }
}

// ---------------- final linear: coalesced wave-per-output ----------------
__global__ void k_final(const unsigned* __restrict__ pooledU, const void* __restrict__ We,
                        void* __restrict__ out, const int* __restrict__ flag) {
    __shared__ float p[512];
    int isf = *flag;
    int b = blockIdx.x >> 2, fb = blockIdx.x & 3;
    int t = threadIdx.x, w = t >> 6, l = t & 63;
    for (int i = t; i < 512; i += 256) p[i] = iordf(pooledU[b * 512 + i]);
    __syncthreads();
    for (int it = 0; it < 16; it++) {
        int f = fb * 64 + w * 16 + it;
        float s = 0.f;
        size_t base = (size_t)f * 512 + l * 8;
#pragma unroll
        for (int j = 0; j < 8; j++) s += p[l * 8 + j] * ldw(We, base + j, isf);
#pragma unroll
        for (int off = 32; off > 0; off >>= 1) s += __shfl_down(s, off);
        if (l == 0) {
            if (isf) ((float*)out)[b * 256 + f] = s;
            else     ((bf16*)out)[b * 256 + f] = f2b(s);
        }
    }
}

extern "C" void kernel_launch(void* const* d_in, const int* in_sizes, int n_in,
                              void* d_out, int out_size, void* d_ws, size_t ws_size,
                              hipStream_t stream) {
    const void* x  = d_in[0];
    const void* Wl[4] = { d_in[1], d_in[4], d_in[7], d_in[10] };
    const void* gl[4] = { d_in[2], d_in[5], d_in[8], d_in[11] };
    const void* bl[4] = { d_in[3], d_in[6], d_in[9], d_in[12] };
    const void* W5 = d_in[13];
    const void* g5 = d_in[14];
    const void* b5 = d_in[15];
    const void* We = d_in[16];

    // workspace layout (bytes): total 8,351,748 <= 8 MiB
    char* base = (char*)d_ws;
    bf16*     xc_hi   = (bf16*)(base);                 // 1,966,080
    bf16*     xc_lo   = (bf16*)(base + 1966080);       // 1,966,080
    bf16*     xpadh   = (bf16*)(base + 3932160);       // 65,536
    bf16*     xpadl   = (bf16*)(base + 3997696);       // 65,536
    float*    DST     = (float*)(base + 4063232);      // 4,194,304 (P)
    int*      idxb    = (int*)(base + 8257536);        // 81,920
    unsigned* pooledU = (unsigned*)(base + 8339456);   // 8,192
    float*    sq      = (float*)(base + 8347648);      // 4,096
    int*      flag    = (int*)(base + 8351744);        // 4

    k_probe<<<1, 256, 0, stream>>>(x, flag, pooledU);

    const int Cs[4]     = { 3, 64, 128, 256 };
    const int Kpad[4]   = { 32, 64, 128, 256 };
    const int Os[4]     = { 64, 128, 256, 512 };
    const int colIn[4]  = { 0, 0, 64, 192 };
    const int colOut[4] = { 0, 64, 192, 448 };

    for (int b = 0; b < NB; b++) {
        k_xpad<<<4, 256, 0, stream>>>(x, b * NPTS * 3, flag, xpadh, xpadl, sq);
        for (int l = 0; l < 4; l++) {
            int O = Os[l];
            const bf16* Xh = (l == 0) ? xpadh : (xc_hi + colIn[l]);
            const bf16* Xl = (l == 0) ? xpadl : (xc_lo + colIn[l]);
            int ld = (l == 0) ? 32 : 960;
            k_distk<<<64, 256, 0, stream>>>(Xh, Xl, ld, Kpad[l], sq, idxb);
            k_st<<<dim3(2 * O / 64, 16), 256, 0, stream>>>(Xh, Xl, ld, Cs[l], Kpad[l],
                                                           Wl[l], O, DST, flag);
            k_gmax<<<NPTS, O, 0, stream>>>(DST, idxb, gl[l], bl[l], O,
                                           xc_hi + colOut[l], xc_lo + colOut[l], sq, l < 3, flag);
        }
        k_conv5<<<dim3(8, 16), 256, 0, stream>>>(xc_hi, xc_lo, W5, g5, b5, pooledU, b, flag);
    }
    k_final<<<16, 256, 0, stream>>>(pooledU, We, d_out, flag);
}

// Round 8
// 969.435 us; speedup vs baseline: 6.3531x; 6.3531x over previous
//
#include <hip/hip_runtime.h>
#include <hip/hip_bf16.h>
#include <math.h>

typedef __hip_bfloat16 bf16;
typedef __bf16 v8bf __attribute__((ext_vector_type(8)));
typedef float v4f __attribute__((ext_vector_type(4)));

#define BN_SCALE 0.9999950000374997f
#define NPTS 1024
#define NB 4
#define TW 40  // LDS tile row stride in bf16 (80B: 2-way bank alias only = free)

__device__ __forceinline__ float b2f(bf16 v) { return __bfloat162float(v); }
__device__ __forceinline__ bf16 f2b(float v) { return __float2bfloat16(v); }
// dtype-flag-aware load: isf=1 -> fp32 data, isf=0 -> bf16 data
__device__ __forceinline__ float ldw(const void* p, size_t i, int isf) {
    return isf ? ((const float*)p)[i] : b2f(((const bf16*)p)[i]);
}
// order-preserving float<->uint transform (monotone increasing)
__device__ __forceinline__ unsigned ordf(float f) {
    unsigned u = __float_as_uint(f);
    return (u & 0x80000000u) ? ~u : (u | 0x80000000u);
}
__device__ __forceinline__ float iordf(unsigned u) {
    return (u & 0x80000000u) ? __uint_as_float(u ^ 0x80000000u) : __uint_as_float(~u);
}

// ---------------- dtype probe (fp32=1 / bf16=0) + pooled init ----------------
__global__ void k_probe(const void* xraw, int* flag, unsigned* pooledU) {
    __shared__ int cnt[256];
    const unsigned short* u = (const unsigned short*)xraw;
    int t = threadIdx.x, c = 0;
    for (int i = t; i < 8192; i += 256) {
        unsigned short v = u[i];
        int e = (v >> 7) & 0xFF;
        int m = v & 0x7F;
        if (e == 0xFF || e >= 141 || (e == 0 && m != 0)) c++;
    }
    cnt[t] = c;
    for (int i = t; i < 2048; i += 256) pooledU[i] = 0u;  // 0 < ordf(any finite)
    __syncthreads();
    for (int off = 128; off > 0; off >>= 1) {
        if (t < off) cnt[t] += cnt[t + off];
        __syncthreads();
    }
    if (t == 0) *flag = (cnt[0] > 200) ? 1 : 0;
}

// fill a 64x32 bf16 tile (rows stride ld) into LDS [64][TW]; 256 threads x 16B
__device__ __forceinline__ void fillA(bf16* dst, const bf16* srcRowBase, int ld) {
    int t = threadIdx.x; int r = t >> 2; int kq = (t & 3) << 3;
    *(float4*)(dst + r * TW + kq) = *(const float4*)(srcRowBase + (size_t)r * ld + kq);
}
// MFMA fragment: sub-tile 'sub' (16 rows), lane l: row=sub*16+(l&15), k=(l>>4)*8
__device__ __forceinline__ v8bf ldfrag(const bf16* tile, int sub, int l) {
    return *(const v8bf*)(tile + (size_t)(sub * 16 + (l & 15)) * TW + ((l >> 4) << 3));
}

// ---------------- layer-1 prep: pad x to 32 cols as hi/lo bf16 split + sq ----------------
__global__ void k_xpad(const void* __restrict__ x, int base, const int* __restrict__ flag,
                       bf16* __restrict__ xph, bf16* __restrict__ xpl, float* __restrict__ sq) {
    int isf = *flag;
    int n = blockIdx.x * 256 + threadIdx.x;
    if (n >= NPTS) return;
    float s = 0.f;
    for (int c = 0; c < 32; c++) {
        float v = (c < 3) ? ldw(x, (size_t)base + n * 3 + c, isf) : 0.f;
        bf16 h = f2b(v);
        xph[n * 32 + c] = h;
        xpl[n * 32 + c] = f2b(v - b2f(h));
        s += v * v;
    }
    sq[n] = s;
}

// ---------------- pairwise d = 2*dot - sq_n - sq_m via MFMA (hi/lo split), symmetric ----------------
__global__ __launch_bounds__(256) void k_dist(const bf16* __restrict__ Xhi, const bf16* __restrict__ Xlo,
                                              int ld, int K,
                                              const float* __restrict__ sq, float* __restrict__ D) {
    int bx = blockIdx.x, by = blockIdx.y;
    if (bx < by) return;
    __shared__ alignas(16) bf16 Ah[64 * TW], Al[64 * TW], Bh[64 * TW], Bl[64 * TW];
    int n0 = by * 64, m0 = bx * 64;
    int w = threadIdx.x >> 6, l = threadIdx.x & 63;
    v4f zero = {0.f, 0.f, 0.f, 0.f};
    v4f acc[4] = {zero, zero, zero, zero};
    for (int k0 = 0; k0 < K; k0 += 32) {
        __syncthreads();
        fillA(Ah, Xhi + (size_t)n0 * ld + k0, ld);
        fillA(Bh, Xhi + (size_t)m0 * ld + k0, ld);
        fillA(Al, Xlo + (size_t)n0 * ld + k0, ld);
        fillA(Bl, Xlo + (size_t)m0 * ld + k0, ld);
        __syncthreads();
        v8bf ah = ldfrag(Ah, w, l);
        v8bf al = ldfrag(Al, w, l);
#pragma unroll
        for (int nt = 0; nt < 4; nt++) {
            v8bf bh = ldfrag(Bh, nt, l);
            v8bf bl = ldfrag(Bl, nt, l);
            acc[nt] = __builtin_amdgcn_mfma_f32_16x16x32_bf16(ah, bh, acc[nt], 0, 0, 0);
            acc[nt] = __builtin_amdgcn_mfma_f32_16x16x32_bf16(ah, bl, acc[nt], 0, 0, 0);
            acc[nt] = __builtin_amdgcn_mfma_f32_16x16x32_bf16(al, bh, acc[nt], 0, 0, 0);
        }
    }
    int quad = l >> 4, col = l & 15;
    int nb = n0 + 16 * w + quad * 4;
    float sm[4];
#pragma unroll
    for (int nt = 0; nt < 4; nt++) sm[nt] = sq[m0 + nt * 16 + col];
#pragma unroll
    for (int r = 0; r < 4; r++) {
        float sn = sq[nb + r];
#pragma unroll
        for (int nt = 0; nt < 4; nt++) {
            float d = 2.f * acc[nt][r] - sn - sm[nt];
            int m = m0 + nt * 16 + col;
            D[(size_t)(nb + r) * NPTS + m] = d;
            if (bx != by) D[(size_t)m * NPTS + nb + r] = d;
        }
    }
}

// ---------------- top-k (k=20): one wave per row, jax tie-break ----------------
__global__ void k_topk(const float* __restrict__ D, int* __restrict__ idx) {
    __shared__ float vals[4][NPTS];
    int w = threadIdx.x >> 6, l = threadIdx.x & 63;
    int row = blockIdx.x * 4 + w;
    const float* Dr = D + (size_t)row * NPTS;
    for (int j = 0; j < 16; j++) vals[w][j * 64 + l] = Dr[j * 64 + l];
    __syncthreads();
    for (int s = 0; s < 20; s++) {
        float bv = -__builtin_inff(); int bi = 0;
#pragma unroll
        for (int j = 0; j < 16; j++) {
            int i = j * 64 + l;
            float v = vals[w][i];
            if (v > bv) { bv = v; bi = i; }
        }
#pragma unroll
        for (int off = 32; off > 0; off >>= 1) {
            float ov = __shfl_down(bv, off);
            int   oi = __shfl_down(bi, off);
            if (ov > bv || (ov == bv && oi < bi)) { bv = ov; bi = oi; }
        }
        if (l == 0) { idx[row * 20 + s] = bi; vals[w][bi] = -__builtin_inff(); }
        __syncthreads();
    }
}

// ---------------- st via MFMA: P[m][0:O)=Wa.x, P[m][O:2O)=Wb.x (W dtype per flag) ----------------
__global__ __launch_bounds__(256) void k_st(const bf16* __restrict__ Xhi, const bf16* __restrict__ Xlo,
                                            int ld, int C, int Kpad,
                                            const void* __restrict__ W, int O, float* __restrict__ P,
                                            const int* __restrict__ flag) {
    __shared__ alignas(16) bf16 Ah[64 * TW], Al[64 * TW], Bh[64 * TW], Bl[64 * TW];
    int isf = *flag;
    int m0 = blockIdx.y * 64, n0 = blockIdx.x * 64;
    int N2 = 2 * O;
    int w = threadIdx.x >> 6, l = threadIdx.x & 63;
    v4f zero = {0.f, 0.f, 0.f, 0.f};
    v4f acc[4] = {zero, zero, zero, zero};
    for (int k0 = 0; k0 < Kpad; k0 += 32) {
        __syncthreads();
        fillA(Ah, Xhi + (size_t)m0 * ld + k0, ld);
        fillA(Al, Xlo + (size_t)m0 * ld + k0, ld);
        {
            int t = threadIdx.x; int r = t >> 2; int kq = (t & 3) << 3;
            int n = n0 + r;
            size_t rowoff = (n < O) ? (size_t)n * 2 * C : (size_t)(n - O) * 2 * C + C;
            for (int j = 0; j < 8; j++) {
                int c = k0 + kq + j;
                float wv = (c < C) ? ldw(W, rowoff + c, isf) : 0.f;
                bf16 h = f2b(wv);
                Bh[r * TW + kq + j] = h;
                Bl[r * TW + kq + j] = f2b(wv - b2f(h));
            }
        }
        __syncthreads();
        v8bf ah = ldfrag(Ah, w, l);
        v8bf al = ldfrag(Al, w, l);
#pragma unroll
        for (int nt = 0; nt < 4; nt++) {
            v8bf bh = ldfrag(Bh, nt, l);
            v8bf bl = ldfrag(Bl, nt, l);
            acc[nt] = __builtin_amdgcn_mfma_f32_16x16x32_bf16(ah, bh, acc[nt], 0, 0, 0);
            acc[nt] = __builtin_amdgcn_mfma_f32_16x16x32_bf16(ah, bl, acc[nt], 0, 0, 0);
            acc[nt] = __builtin_amdgcn_mfma_f32_16x16x32_bf16(al, bh, acc[nt], 0, 0, 0);
        }
    }
    int quad = l >> 4, col = l & 15;
    int rb = m0 + 16 * w + quad * 4;
#pragma unroll
    for (int r = 0; r < 4; r++)
#pragma unroll
        for (int nt = 0; nt < 4; nt++)
            P[(size_t)(rb + r) * N2 + n0 + nt * 16 + col] = acc[nt][r];
}

// ---------------- conv5 via MFMA + fused affine/lrelu/max-pool via atomicMax ----------------
__global__ __launch_bounds__(256) void k_conv5(const bf16* __restrict__ Xhi, const bf16* __restrict__ Xlo,
                                               const void* __restrict__ W,
                                               const void* __restrict__ g, const void* __restrict__ bias,
                                               unsigned* __restrict__ pooledU, int b,
                                               const int* __restrict__ flag) {
    __shared__ alignas(16) bf16 Ah[64 * TW], Al[64 * TW], Bh[64 * TW], Bl[64 * TW];
    __shared__ float red[4][4][16];
    int isf = *flag;
    int m0 = blockIdx.y * 64, o0 = blockIdx.x * 64;
    int w = threadIdx.x >> 6, l = threadIdx.x & 63;
    v4f zero = {0.f, 0.f, 0.f, 0.f};
    v4f acc[4] = {zero, zero, zero, zero};
    for (int k0 = 0; k0 < 960; k0 += 32) {
        __syncthreads();
        fillA(Ah, Xhi + (size_t)m0 * 960 + k0, 960);
        fillA(Al, Xlo + (size_t)m0 * 960 + k0, 960);
        {
            int t = threadIdx.x; int r = t >> 2; int kq = (t & 3) << 3;
            size_t rowoff = (size_t)(o0 + r) * 960;
            for (int j = 0; j < 8; j++) {
                float wv = ldw(W, rowoff + k0 + kq + j, isf);
                bf16 h = f2b(wv);
                Bh[r * TW + kq + j] = h;
                Bl[r * TW + kq + j] = f2b(wv - b2f(h));
            }
        }
        __syncthreads();
        v8bf ah = ldfrag(Ah, w, l);
        v8bf al = ldfrag(Al, w, l);
#pragma unroll
        for (int nt = 0; nt < 4; nt++) {
            v8bf bh = ldfrag(Bh, nt, l);
            v8bf bl = ldfrag(Bl, nt, l);
            acc[nt] = __builtin_amdgcn_mfma_f32_16x16x32_bf16(ah, bh, acc[nt], 0, 0, 0);
            acc[nt] = __builtin_amdgcn_mfma_f32_16x16x32_bf16(ah, bl, acc[nt], 0, 0, 0);
            acc[nt] = __builtin_amdgcn_mfma_f32_16x16x32_bf16(al, bh, acc[nt], 0, 0, 0);
        }
    }
    int quad = l >> 4, col = l & 15;
#pragma unroll
    for (int nt = 0; nt < 4; nt++) {
        int o = o0 + nt * 16 + col;
        float scl = ldw(g, o, isf) * BN_SCALE;
        float bi = ldw(bias, o, isf);
        float ym = -__builtin_inff();
#pragma unroll
        for (int r = 0; r < 4; r++) {
            float v = acc[nt][r] * scl + bi;
            v = v > 0.f ? v : 0.2f * v;
            ym = fmaxf(ym, v);
        }
        ym = fmaxf(ym, __shfl_down(ym, 32));
        ym = fmaxf(ym, __shfl_down(ym, 16));
        if (quad == 0) red[w][nt][col] = ym;
    }
    __syncthreads();
    if (threadIdx.x < 64) {
        int nt = threadIdx.x >> 4, c = threadIdx.x & 15;
        float m = fmaxf(fmaxf(red[0][nt][c], red[1][nt][c]), fmaxf(red[2][nt][c], red[3][nt][c]));
        atomicMax(&pooledU[b * 512 + o0 + nt * 16 + c], ordf(m));
    }
}

// ---------------- gather + affine + lrelu + max over k -> xc hi/lo; fused sq ----------------
__global__ void k_gmax(const float* __restrict__ P, const int* __restrict__ idx,
                       const void* __restrict__ g, const void* __restrict__ bias, int O,
                       bf16* __restrict__ xhOut, bf16* __restrict__ xlOut,
                       float* __restrict__ sqOut, int writeSq, const int* __restrict__ flag) {
    __shared__ int id[20];
    __shared__ float red[8];
    int isf = *flag;
    int n = blockIdx.x;
    int o = threadIdx.x;  // blockDim.x == O
    if (o < 20) id[o] = idx[n * 20 + o];
    __syncthreads();
    int N2 = 2 * O;
    float tv = P[(size_t)n * N2 + O + o] - P[(size_t)n * N2 + o];
    float scl = ldw(g, o, isf) * BN_SCALE;
    float bi = ldw(bias, o, isf);
    float acc = -__builtin_inff();
    for (int j = 0; j < 20; j++) {
        int m = id[j];
        float v = P[(size_t)m * N2 + o] + tv;
        float z = v * scl + bi;
        z = z > 0.f ? z : 0.2f * z;
        acc = fmaxf(acc, z);
    }
    bf16 hi = f2b(acc);
    bf16 lo = f2b(acc - b2f(hi));
    xhOut[(size_t)n * 960 + o] = hi;
    xlOut[(size_t)n * 960 + o] = lo;
    if (writeSq) {
        float xv = b2f(hi) + b2f(lo);
        float s = xv * xv;
#pragma unroll
        for (int off = 32; off > 0; off >>= 1) s += __shfl_down(s, off);
        if ((o & 63) == 0) red[o >> 6] = s;
        __syncthreads();
        if (o == 0) {
            float tot = 0.f;
            for (int i = 0; i < (O >> 6); i++) tot += red[i];
            sqOut[n] = tot;
        }
    }
}

// ---------------- final linear: coalesced wave-per-output ----------------
__global__ void k_final(const unsigned* __restrict__ pooledU, const void* __restrict__ We,
                        void* __restrict__ out, const int* __restrict__ flag) {
    __shared__ float p[512];
    int isf = *flag;
    int b = blockIdx.x >> 2, fb = blockIdx.x & 3;
    int t = threadIdx.x, w = t >> 6, l = t & 63;
    for (int i = t; i < 512; i += 256) p[i] = iordf(pooledU[b * 512 + i]);
    __syncthreads();
    for (int it = 0; it < 16; it++) {
        int f = fb * 64 + w * 16 + it;
        float s = 0.f;
        size_t base = (size_t)f * 512 + l * 8;
#pragma unroll
        for (int j = 0; j < 8; j++) s += p[l * 8 + j] * ldw(We, base + j, isf);
#pragma unroll
        for (int off = 32; off > 0; off >>= 1) s += __shfl_down(s, off);
        if (l == 0) {
            if (isf) ((float*)out)[b * 256 + f] = s;
            else     ((bf16*)out)[b * 256 + f] = f2b(s);
        }
    }
}

extern "C" void kernel_launch(void* const* d_in, const int* in_sizes, int n_in,
                              void* d_out, int out_size, void* d_ws, size_t ws_size,
                              hipStream_t stream) {
    const void* x  = d_in[0];
    const void* Wl[4] = { d_in[1], d_in[4], d_in[7], d_in[10] };
    const void* gl[4] = { d_in[2], d_in[5], d_in[8], d_in[11] };
    const void* bl[4] = { d_in[3], d_in[6], d_in[9], d_in[12] };
    const void* W5 = d_in[13];
    const void* g5 = d_in[14];
    const void* b5 = d_in[15];
    const void* We = d_in[16];

    // workspace layout (bytes): total 8,351,748 <= 8 MiB
    char* base = (char*)d_ws;
    bf16*     xc_hi   = (bf16*)(base);                 // 1,966,080
    bf16*     xc_lo   = (bf16*)(base + 1966080);       // 1,966,080
    bf16*     xpadh   = (bf16*)(base + 3932160);       // 65,536
    bf16*     xpadl   = (bf16*)(base + 3997696);       // 65,536
    float*    DST     = (float*)(base + 4063232);      // 4,194,304 (D | P)
    int*      idxb    = (int*)(base + 8257536);        // 81,920
    unsigned* pooledU = (unsigned*)(base + 8339456);   // 8,192
    float*    sq      = (float*)(base + 8347648);      // 4,096
    int*      flag    = (int*)(base + 8351744);        // 4

    k_probe<<<1, 256, 0, stream>>>(x, flag, pooledU);

    const int Cs[4]     = { 3, 64, 128, 256 };
    const int Kpad[4]   = { 32, 64, 128, 256 };
    const int Os[4]     = { 64, 128, 256, 512 };
    const int colIn[4]  = { 0, 0, 64, 192 };
    const int colOut[4] = { 0, 64, 192, 448 };

    for (int b = 0; b < NB; b++) {
        k_xpad<<<4, 256, 0, stream>>>(x, b * NPTS * 3, flag, xpadh, xpadl, sq);
        for (int l = 0; l < 4; l++) {
            int O = Os[l];
            const bf16* Xh = (l == 0) ? xpadh : (xc_hi + colIn[l]);
            const bf16* Xl = (l == 0) ? xpadl : (xc_lo + colIn[l]);
            int ld = (l == 0) ? 32 : 960;
            k_dist<<<dim3(16, 16), 256, 0, stream>>>(Xh, Xl, ld, Kpad[l], sq, DST);
            k_topk<<<NPTS / 4, 256, 0, stream>>>(DST, idxb);
            k_st<<<dim3(2 * O / 64, 16), 256, 0, stream>>>(Xh, Xl, ld, Cs[l], Kpad[l],
                                                           Wl[l], O, DST, flag);
            k_gmax<<<NPTS, O, 0, stream>>>(DST, idxb, gl[l], bl[l], O,
                                           xc_hi + colOut[l], xc_lo + colOut[l], sq, l < 3, flag);
        }
        k_conv5<<<dim3(8, 16), 256, 0, stream>>>(xc_hi, xc_lo, W5, g5, b5, pooledU, b, flag);
    }
    k_final<<<16, 256, 0, stream>>>(pooledU, We, d_out, flag);
}

// Round 9
// 857.283 us; speedup vs baseline: 7.1842x; 1.1308x over previous
//
#include <hip/hip_runtime.h>
#include <hip/hip_bf16.h>
#include <math.h>

typedef __hip_bfloat16 bf16;
typedef __bf16 v8bf __attribute__((ext_vector_type(8)));
typedef float v4f __attribute__((ext_vector_type(4)));

#define BN_SCALE 0.9999950000374997f
#define NPTS 1024
#define NB 4
#define TW 40  // LDS tile row stride in bf16 (80B: 2-way bank alias only = free)

__device__ __forceinline__ float b2f(bf16 v) { return __bfloat162float(v); }
__device__ __forceinline__ bf16 f2b(float v) { return __float2bfloat16(v); }
// dtype-flag-aware load: isf=1 -> fp32 data, isf=0 -> bf16 data
__device__ __forceinline__ float ldw(const void* p, size_t i, int isf) {
    return isf ? ((const float*)p)[i] : b2f(((const bf16*)p)[i]);
}
// order-preserving float<->uint transform (monotone increasing)
__device__ __forceinline__ unsigned ordf(float f) {
    unsigned u = __float_as_uint(f);
    return (u & 0x80000000u) ? ~u : (u | 0x80000000u);
}
__device__ __forceinline__ float iordf(unsigned u) {
    return (u & 0x80000000u) ? __uint_as_float(u ^ 0x80000000u) : __uint_as_float(~u);
}

// ---------------- dtype probe (fp32=1 / bf16=0) + pooled init ----------------
__global__ void k_probe(const void* xraw, int* flag, unsigned* pooledU) {
    __shared__ int cnt[256];
    const unsigned short* u = (const unsigned short*)xraw;
    int t = threadIdx.x, c = 0;
    for (int i = t; i < 8192; i += 256) {
        unsigned short v = u[i];
        int e = (v >> 7) & 0xFF;
        int m = v & 0x7F;
        if (e == 0xFF || e >= 141 || (e == 0 && m != 0)) c++;
    }
    cnt[t] = c;
    for (int i = t; i < 2048; i += 256) pooledU[i] = 0u;  // 0 < ordf(any finite)
    __syncthreads();
    for (int off = 128; off > 0; off >>= 1) {
        if (t < off) cnt[t] += cnt[t + off];
        __syncthreads();
    }
    if (t == 0) *flag = (cnt[0] > 200) ? 1 : 0;
}

// fill a 64x32 bf16 tile (rows stride ld) into LDS [64][TW]; 256 threads x 16B
__device__ __forceinline__ void fillA(bf16* dst, const bf16* srcRowBase, int ld) {
    int t = threadIdx.x; int r = t >> 2; int kq = (t & 3) << 3;
    *(float4*)(dst + r * TW + kq) = *(const float4*)(srcRowBase + (size_t)r * ld + kq);
}
// MFMA fragment: sub-tile 'sub' (16 rows), lane l: row=sub*16+(l&15), k=(l>>4)*8
__device__ __forceinline__ v8bf ldfrag(const bf16* tile, int sub, int l) {
    return *(const v8bf*)(tile + (size_t)(sub * 16 + (l & 15)) * TW + ((l >> 4) << 3));
}

// stage 8 W elements as packed hi/lo bf16 into LDS (vector path, C%8==0)
__device__ __forceinline__ void stageW8(const void* W, size_t off, int isf,
                                        bf16* Bh, bf16* Bl, int dst) {
    if (isf) {
        const float* Wf = (const float*)W;
        float4 f0 = *(const float4*)(Wf + off);
        float4 f1 = *(const float4*)(Wf + off + 4);
        float fv[8] = { f0.x, f0.y, f0.z, f0.w, f1.x, f1.y, f1.z, f1.w };
        alignas(16) bf16 th[8], tl[8];
#pragma unroll
        for (int j = 0; j < 8; j++) {
            bf16 h = f2b(fv[j]);
            th[j] = h;
            tl[j] = f2b(fv[j] - b2f(h));
        }
        *(v8bf*)&Bh[dst] = *(const v8bf*)th;
        *(v8bf*)&Bl[dst] = *(const v8bf*)tl;
    } else {
        *(v8bf*)&Bh[dst] = *(const v8bf*)((const bf16*)W + off);  // exact; lo == 0, skipped in MFMA
    }
}

// ---------------- layer-1 prep: pad x to 32 cols as hi/lo bf16 split + sq ----------------
__global__ void k_xpad(const void* __restrict__ x, int base, const int* __restrict__ flag,
                       bf16* __restrict__ xph, bf16* __restrict__ xpl, float* __restrict__ sq) {
    int isf = *flag;
    int n = blockIdx.x * 256 + threadIdx.x;
    if (n >= NPTS) return;
    float s = 0.f;
    for (int c = 0; c < 32; c++) {
        float v = (c < 3) ? ldw(x, (size_t)base + n * 3 + c, isf) : 0.f;
        bf16 h = f2b(v);
        xph[n * 32 + c] = h;
        xpl[n * 32 + c] = f2b(v - b2f(h));
        s += v * v;
    }
    sq[n] = s;
}

// ---------------- pairwise d = 2*dot - sq_n - sq_m via MFMA (hi/lo split), symmetric ----------------
__global__ __launch_bounds__(256) void k_dist(const bf16* __restrict__ Xhi, const bf16* __restrict__ Xlo,
                                              int ld, int K,
                                              const float* __restrict__ sq, float* __restrict__ D) {
    int bx = blockIdx.x, by = blockIdx.y;
    if (bx < by) return;
    __shared__ alignas(16) bf16 Ah[64 * TW], Al[64 * TW], Bh[64 * TW], Bl[64 * TW];
    int n0 = by * 64, m0 = bx * 64;
    int w = threadIdx.x >> 6, l = threadIdx.x & 63;
    v4f zero = {0.f, 0.f, 0.f, 0.f};
    v4f acc[4] = {zero, zero, zero, zero};
    for (int k0 = 0; k0 < K; k0 += 32) {
        __syncthreads();
        fillA(Ah, Xhi + (size_t)n0 * ld + k0, ld);
        fillA(Bh, Xhi + (size_t)m0 * ld + k0, ld);
        fillA(Al, Xlo + (size_t)n0 * ld + k0, ld);
        fillA(Bl, Xlo + (size_t)m0 * ld + k0, ld);
        __syncthreads();
        v8bf ah = ldfrag(Ah, w, l);
        v8bf al = ldfrag(Al, w, l);
#pragma unroll
        for (int nt = 0; nt < 4; nt++) {
            v8bf bh = ldfrag(Bh, nt, l);
            v8bf bl = ldfrag(Bl, nt, l);
            acc[nt] = __builtin_amdgcn_mfma_f32_16x16x32_bf16(ah, bh, acc[nt], 0, 0, 0);
            acc[nt] = __builtin_amdgcn_mfma_f32_16x16x32_bf16(ah, bl, acc[nt], 0, 0, 0);
            acc[nt] = __builtin_amdgcn_mfma_f32_16x16x32_bf16(al, bh, acc[nt], 0, 0, 0);
        }
    }
    int quad = l >> 4, col = l & 15;
    int nb = n0 + 16 * w + quad * 4;
    float sm[4];
#pragma unroll
    for (int nt = 0; nt < 4; nt++) sm[nt] = sq[m0 + nt * 16 + col];
#pragma unroll
    for (int r = 0; r < 4; r++) {
        float sn = sq[nb + r];
#pragma unroll
        for (int nt = 0; nt < 4; nt++) {
            float d = 2.f * acc[nt][r] - sn - sm[nt];
            int m = m0 + nt * 16 + col;
            D[(size_t)(nb + r) * NPTS + m] = d;
            if (bx != by) D[(size_t)m * NPTS + nb + r] = d;
        }
    }
}

// ---------------- top-k (k=20): register-resident, wave per row, no LDS/barriers ----------------
__global__ __launch_bounds__(256) void k_topk(const float* __restrict__ D, int* __restrict__ idx) {
    int w = threadIdx.x >> 6, l = threadIdx.x & 63;
    int row = blockIdx.x * 4 + w;
    const float* Dr = D + (size_t)row * NPTS;
    float v[16];
#pragma unroll
    for (int j = 0; j < 16; j++) v[j] = Dr[j * 64 + l];
    for (int s = 0; s < 20; s++) {
        float bv = v[0]; int bj = 0;
#pragma unroll
        for (int j = 1; j < 16; j++)
            if (v[j] > bv) { bv = v[j]; bj = j; }   // ascending keeps min j on tie
        int bi = bj * 64 + l;
#pragma unroll
        for (int off = 1; off < 64; off <<= 1) {   // xor butterfly: all lanes converge
            float ov = __shfl_xor(bv, off);
            int   oi = __shfl_xor(bi, off);
            if (ov > bv || (ov == bv && oi < bi)) { bv = ov; bi = oi; }
        }
        if (l == 0) idx[row * 20 + s] = bi;
        if ((bi & 63) == l) {                       // owning lane evicts
            int ej = bi >> 6;
#pragma unroll
            for (int j = 0; j < 16; j++)
                if (j == ej) v[j] = -__builtin_inff();
        }
    }
}

// ---------------- st via MFMA: P[m][0:O)=Wa.x, P[m][O:2O)=Wb.x (W dtype per flag) ----------------
__global__ __launch_bounds__(256) void k_st(const bf16* __restrict__ Xhi, const bf16* __restrict__ Xlo,
                                            int ld, int C, int Kpad,
                                            const void* __restrict__ W, int O, float* __restrict__ P,
                                            const int* __restrict__ flag) {
    __shared__ alignas(16) bf16 Ah[64 * TW], Al[64 * TW], Bh[64 * TW], Bl[64 * TW];
    int isf = *flag;
    int m0 = blockIdx.y * 64, n0 = blockIdx.x * 64;
    int N2 = 2 * O;
    int w = threadIdx.x >> 6, l = threadIdx.x & 63;
    v4f zero = {0.f, 0.f, 0.f, 0.f};
    v4f acc[4] = {zero, zero, zero, zero};
    for (int k0 = 0; k0 < Kpad; k0 += 32) {
        __syncthreads();
        fillA(Ah, Xhi + (size_t)m0 * ld + k0, ld);
        fillA(Al, Xlo + (size_t)m0 * ld + k0, ld);
        {
            int t = threadIdx.x; int r = t >> 2; int kq = (t & 3) << 3;
            int n = n0 + r;
            size_t rowoff = (n < O) ? (size_t)n * 2 * C : (size_t)(n - O) * 2 * C + C;
            if ((C & 7) == 0) {
                stageW8(W, rowoff + k0 + kq, isf, Bh, Bl, r * TW + kq);
            } else {  // layer-1 fallback (C=3)
                bf16 z = f2b(0.f);
                for (int j = 0; j < 8; j++) {
                    int c = k0 + kq + j;
                    float wv = (c < C) ? ldw(W, rowoff + c, isf) : 0.f;
                    bf16 h = f2b(wv);
                    Bh[r * TW + kq + j] = h;
                    Bl[r * TW + kq + j] = isf ? f2b(wv - b2f(h)) : z;
                }
            }
        }
        __syncthreads();
        v8bf ah = ldfrag(Ah, w, l);
        v8bf al = ldfrag(Al, w, l);
#pragma unroll
        for (int nt = 0; nt < 4; nt++) {
            v8bf bh = ldfrag(Bh, nt, l);
            acc[nt] = __builtin_amdgcn_mfma_f32_16x16x32_bf16(ah, bh, acc[nt], 0, 0, 0);
            acc[nt] = __builtin_amdgcn_mfma_f32_16x16x32_bf16(al, bh, acc[nt], 0, 0, 0);
            if (isf || (C & 7)) {  // W-lo exists only for fp32 weights (bf16: lo==0)
                v8bf bl = ldfrag(Bl, nt, l);
                acc[nt] = __builtin_amdgcn_mfma_f32_16x16x32_bf16(ah, bl, acc[nt], 0, 0, 0);
            }
        }
    }
    int quad = l >> 4, col = l & 15;
    int rb = m0 + 16 * w + quad * 4;
#pragma unroll
    for (int r = 0; r < 4; r++)
#pragma unroll
        for (int nt = 0; nt < 4; nt++)
            P[(size_t)(rb + r) * N2 + n0 + nt * 16 + col] = acc[nt][r];
}

// ---------------- conv5 via MFMA + fused affine/lrelu/max-pool via atomicMax ----------------
__global__ __launch_bounds__(256) void k_conv5(const bf16* __restrict__ Xhi, const bf16* __restrict__ Xlo,
                                               const void* __restrict__ W,
                                               const void* __restrict__ g, const void* __restrict__ bias,
                                               unsigned* __restrict__ pooledU, int b,
                                               const int* __restrict__ flag) {
    __shared__ alignas(16) bf16 Ah[64 * TW], Al[64 * TW], Bh[64 * TW], Bl[64 * TW];
    __shared__ float red[4][4][16];
    int isf = *flag;
    int m0 = blockIdx.y * 64, o0 = blockIdx.x * 64;
    int w = threadIdx.x >> 6, l = threadIdx.x & 63;
    v4f zero = {0.f, 0.f, 0.f, 0.f};
    v4f acc[4] = {zero, zero, zero, zero};
    for (int k0 = 0; k0 < 960; k0 += 32) {
        __syncthreads();
        fillA(Ah, Xhi + (size_t)m0 * 960 + k0, 960);
        fillA(Al, Xlo + (size_t)m0 * 960 + k0, 960);
        {
            int t = threadIdx.x; int r = t >> 2; int kq = (t & 3) << 3;
            stageW8(W, (size_t)(o0 + r) * 960 + k0 + kq, isf, Bh, Bl, r * TW + kq);
        }
        __syncthreads();
        v8bf ah = ldfrag(Ah, w, l);
        v8bf al = ldfrag(Al, w, l);
#pragma unroll
        for (int nt = 0; nt < 4; nt++) {
            v8bf bh = ldfrag(Bh, nt, l);
            acc[nt] = __builtin_amdgcn_mfma_f32_16x16x32_bf16(ah, bh, acc[nt], 0, 0, 0);
            acc[nt] = __builtin_amdgcn_mfma_f32_16x16x32_bf16(al, bh, acc[nt], 0, 0, 0);
            if (isf) {
                v8bf bl = ldfrag(Bl, nt, l);
                acc[nt] = __builtin_amdgcn_mfma_f32_16x16x32_bf16(ah, bl, acc[nt], 0, 0, 0);
            }
        }
    }
    int quad = l >> 4, col = l & 15;
#pragma unroll
    for (int nt = 0; nt < 4; nt++) {
        int o = o0 + nt * 16 + col;
        float scl = ldw(g, o, isf) * BN_SCALE;
        float bi = ldw(bias, o, isf);
        float ym = -__builtin_inff();
#pragma unroll
        for (int r = 0; r < 4; r++) {
            float v = acc[nt][r] * scl + bi;
            v = v > 0.f ? v : 0.2f * v;
            ym = fmaxf(ym, v);
        }
        ym = fmaxf(ym, __shfl_down(ym, 32));
        ym = fmaxf(ym, __shfl_down(ym, 16));
        if (quad == 0) red[w][nt][col] = ym;
    }
    __syncthreads();
    if (threadIdx.x < 64) {
        int nt = threadIdx.x >> 4, c = threadIdx.x & 15;
        float m = fmaxf(fmaxf(red[0][nt][c], red[1][nt][c]), fmaxf(red[2][nt][c], red[3][nt][c]));
        atomicMax(&pooledU[b * 512 + o0 + nt * 16 + c], ordf(m));
    }
}

// ---------------- gather + affine + lrelu + max over k -> xc hi/lo; fused sq ----------------
__global__ void k_gmax(const float* __restrict__ P, const int* __restrict__ idx,
                       const void* __restrict__ g, const void* __restrict__ bias, int O,
                       bf16* __restrict__ xhOut, bf16* __restrict__ xlOut,
                       float* __restrict__ sqOut, int writeSq, const int* __restrict__ flag) {
    __shared__ int id[20];
    __shared__ float red[8];
    int isf = *flag;
    int n = blockIdx.x;
    int o = threadIdx.x;  // blockDim.x == O
    if (o < 20) id[o] = idx[n * 20 + o];
    __syncthreads();
    int N2 = 2 * O;
    float tv = P[(size_t)n * N2 + O + o] - P[(size_t)n * N2 + o];
    float scl = ldw(g, o, isf) * BN_SCALE;
    float bi = ldw(bias, o, isf);
    float acc = -__builtin_inff();
    for (int j = 0; j < 20; j++) {
        int m = id[j];
        float v = P[(size_t)m * N2 + o] + tv;
        float z = v * scl + bi;
        z = z > 0.f ? z : 0.2f * z;
        acc = fmaxf(acc, z);
    }
    bf16 hi = f2b(acc);
    bf16 lo = f2b(acc - b2f(hi));
    xhOut[(size_t)n * 960 + o] = hi;
    xlOut[(size_t)n * 960 + o] = lo;
    if (writeSq) {
        float xv = b2f(hi) + b2f(lo);
        float s = xv * xv;
#pragma unroll
        for (int off = 32; off > 0; off >>= 1) s += __shfl_down(s, off);
        if ((o & 63) == 0) red[o >> 6] = s;
        __syncthreads();
        if (o == 0) {
            float tot = 0.f;
            for (int i = 0; i < (O >> 6); i++) tot += red[i];
            sqOut[n] = tot;
        }
    }
}

// ---------------- final linear: coalesced wave-per-output ----------------
__global__ void k_final(const unsigned* __restrict__ pooledU, const void* __restrict__ We,
                        void* __restrict__ out, const int* __restrict__ flag) {
    __shared__ float p[512];
    int isf = *flag;
    int b = blockIdx.x >> 2, fb = blockIdx.x & 3;
    int t = threadIdx.x, w = t >> 6, l = t & 63;
    for (int i = t; i < 512; i += 256) p[i] = iordf(pooledU[b * 512 + i]);
    __syncthreads();
    for (int it = 0; it < 16; it++) {
        int f = fb * 64 + w * 16 + it;
        float s = 0.f;
        size_t base = (size_t)f * 512 + l * 8;
#pragma unroll
        for (int j = 0; j < 8; j++) s += p[l * 8 + j] * ldw(We, base + j, isf);
#pragma unroll
        for (int off = 32; off > 0; off >>= 1) s += __shfl_down(s, off);
        if (l == 0) {
            if (isf) ((float*)out)[b * 256 + f] = s;
            else     ((bf16*)out)[b * 256 + f] = f2b(s);
        }
    }
}

extern "C" void kernel_launch(void* const* d_in, const int* in_sizes, int n_in,
                              void* d_out, int out_size, void* d_ws, size_t ws_size,
                              hipStream_t stream) {
    const void* x  = d_in[0];
    const void* Wl[4] = { d_in[1], d_in[4], d_in[7], d_in[10] };
    const void* gl[4] = { d_in[2], d_in[5], d_in[8], d_in[11] };
    const void* bl[4] = { d_in[3], d_in[6], d_in[9], d_in[12] };
    const void* W5 = d_in[13];
    const void* g5 = d_in[14];
    const void* b5 = d_in[15];
    const void* We = d_in[16];

    // workspace layout (bytes): total 8,351,748 <= 8 MiB
    char* base = (char*)d_ws;
    bf16*     xc_hi   = (bf16*)(base);                 // 1,966,080
    bf16*     xc_lo   = (bf16*)(base + 1966080);       // 1,966,080
    bf16*     xpadh   = (bf16*)(base + 3932160);       // 65,536
    bf16*     xpadl   = (bf16*)(base + 3997696);       // 65,536
    float*    DST     = (float*)(base + 4063232);      // 4,194,304 (D | P)
    int*      idxb    = (int*)(base + 8257536);        // 81,920
    unsigned* pooledU = (unsigned*)(base + 8339456);   // 8,192
    float*    sq      = (float*)(base + 8347648);      // 4,096
    int*      flag    = (int*)(base + 8351744);        // 4

    k_probe<<<1, 256, 0, stream>>>(x, flag, pooledU);

    const int Cs[4]     = { 3, 64, 128, 256 };
    const int Kpad[4]   = { 32, 64, 128, 256 };
    const int Os[4]     = { 64, 128, 256, 512 };
    const int colIn[4]  = { 0, 0, 64, 192 };
    const int colOut[4] = { 0, 64, 192, 448 };

    for (int b = 0; b < NB; b++) {
        k_xpad<<<4, 256, 0, stream>>>(x, b * NPTS * 3, flag, xpadh, xpadl, sq);
        for (int l = 0; l < 4; l++) {
            int O = Os[l];
            const bf16* Xh = (l == 0) ? xpadh : (xc_hi + colIn[l]);
            const bf16* Xl = (l == 0) ? xpadl : (xc_lo + colIn[l]);
            int ld = (l == 0) ? 32 : 960;
            k_dist<<<dim3(16, 16), 256, 0, stream>>>(Xh, Xl, ld, Kpad[l], sq, DST);
            k_topk<<<NPTS / 4, 256, 0, stream>>>(DST, idxb);
            k_st<<<dim3(2 * O / 64, 16), 256, 0, stream>>>(Xh, Xl, ld, Cs[l], Kpad[l],
                                                           Wl[l], O, DST, flag);
            k_gmax<<<NPTS, O, 0, stream>>>(DST, idxb, gl[l], bl[l], O,
                                           xc_hi + colOut[l], xc_lo + colOut[l], sq, l < 3, flag);
        }
        k_conv5<<<dim3(8, 16), 256, 0, stream>>>(xc_hi, xc_lo, W5, g5, b5, pooledU, b, flag);
    }
    k_final<<<16, 256, 0, stream>>>(pooledU, We, d_out, flag);
}

// Round 10
// 401.363 us; speedup vs baseline: 15.3450x; 2.1359x over previous
//
#include <hip/hip_runtime.h>
#include <hip/hip_bf16.h>
#include <math.h>

typedef __hip_bfloat16 bf16;
typedef __bf16 v8bf __attribute__((ext_vector_type(8)));
typedef float v4f __attribute__((ext_vector_type(4)));

#define BN_SCALE 0.9999950000374997f
#define NPTS 1024
#define NB 4
#define TW 40  // LDS tile row stride in bf16 (80B: 2-way bank alias only = free)

__device__ __forceinline__ float b2f(bf16 v) { return __bfloat162float(v); }
__device__ __forceinline__ bf16 f2b(float v) { return __float2bfloat16(v); }
// dtype-flag-aware load: isf=1 -> fp32 data, isf=0 -> bf16 data
__device__ __forceinline__ float ldw(const void* p, size_t i, int isf) {
    return isf ? ((const float*)p)[i] : b2f(((const bf16*)p)[i]);
}
// order-preserving float<->uint transform (monotone increasing)
__device__ __forceinline__ unsigned ordf(float f) {
    unsigned u = __float_as_uint(f);
    return (u & 0x80000000u) ? ~u : (u | 0x80000000u);
}
__device__ __forceinline__ float iordf(unsigned u) {
    return (u & 0x80000000u) ? __uint_as_float(u ^ 0x80000000u) : __uint_as_float(~u);
}

// ---------------- dtype probe (fp32=1 / bf16=0) + pooled init ----------------
__global__ void k_probe(const void* xraw, int* flag, unsigned* pooledU) {
    __shared__ int cnt[256];
    const unsigned short* u = (const unsigned short*)xraw;
    int t = threadIdx.x, c = 0;
    for (int i = t; i < 8192; i += 256) {
        unsigned short v = u[i];
        int e = (v >> 7) & 0xFF;
        int m = v & 0x7F;
        if (e == 0xFF || e >= 141 || (e == 0 && m != 0)) c++;
    }
    cnt[t] = c;
    for (int i = t; i < 2048; i += 256) pooledU[i] = 0u;  // 0 < ordf(any finite)
    __syncthreads();
    for (int off = 128; off > 0; off >>= 1) {
        if (t < off) cnt[t] += cnt[t + off];
        __syncthreads();
    }
    if (t == 0) *flag = (cnt[0] > 200) ? 1 : 0;
}

// ---------------- weight pre-split into MFMA-ready bf16 hi/lo [rows][Kpad] ----------------
// twoRows=1: st layout (rows 2O: n<O -> Wa row n, n>=O -> Wb row n-O), src (O,2C)
// twoRows=0: plain (rows O), src (O,C)
__global__ void k_wsplit(const void* __restrict__ Wsrc, int C, int O, int Kpad, int twoRows,
                         bf16* __restrict__ dh, bf16* __restrict__ dl,
                         const int* __restrict__ flag) {
    int isf = *flag;
    int rows = twoRows ? 2 * O : O;
    int idx = blockIdx.x * 256 + threadIdx.x;
    if (idx >= rows * Kpad) return;
    int r = idx / Kpad, c = idx % Kpad;
    float wv = 0.f;
    if (c < C) {
        size_t off;
        if (twoRows) off = (r < O) ? (size_t)r * 2 * C + c : (size_t)(r - O) * 2 * C + C + c;
        else         off = (size_t)r * C + c;
        wv = ldw(Wsrc, off, isf);
    }
    bf16 h = f2b(wv);
    dh[idx] = h;
    dl[idx] = f2b(wv - b2f(h));
}

// fill a 64x32 bf16 tile (rows stride ld) into LDS [64][TW]; 256 threads x 16B
__device__ __forceinline__ void fillA(bf16* dst, const bf16* srcRowBase, int ld) {
    int t = threadIdx.x; int r = t >> 2; int kq = (t & 3) << 3;
    *(float4*)(dst + r * TW + kq) = *(const float4*)(srcRowBase + (size_t)r * ld + kq);
}
// MFMA fragment: sub-tile 'sub' (16 rows), lane l: row=sub*16+(l&15), k=(l>>4)*8
__device__ __forceinline__ v8bf ldfrag(const bf16* tile, int sub, int l) {
    return *(const v8bf*)(tile + (size_t)(sub * 16 + (l & 15)) * TW + ((l >> 4) << 3));
}

// ---------------- layer-1 prep (all batches): pad x to 32 cols hi/lo + sq ----------------
__global__ void k_xpad(const void* __restrict__ x, const int* __restrict__ flag,
                       bf16* __restrict__ xph, bf16* __restrict__ xpl, float* __restrict__ sq) {
    int isf = *flag;
    int z = blockIdx.y;
    int n = blockIdx.x * 256 + threadIdx.x;
    if (n >= NPTS) return;
    size_t inb = (size_t)z * NPTS * 3;
    bf16* ph = xph + (size_t)z * NPTS * 32;
    bf16* pl = xpl + (size_t)z * NPTS * 32;
    float s = 0.f;
    for (int c = 0; c < 32; c++) {
        float v = (c < 3) ? ldw(x, inb + n * 3 + c, isf) : 0.f;
        bf16 h = f2b(v);
        ph[n * 32 + c] = h;
        pl[n * 32 + c] = f2b(v - b2f(h));
        s += v * v;
    }
    sq[z * NPTS + n] = s;
}

// ---------------- pairwise d = 2*dot - sq_n - sq_m via MFMA (hi/lo), symmetric, batched ----------------
__global__ __launch_bounds__(256) void k_dist(const bf16* __restrict__ Xhi, const bf16* __restrict__ Xlo,
                                              int ld, int K, size_t xstride,
                                              const float* __restrict__ sqg, float* __restrict__ Dg) {
    int bx = blockIdx.x, by = blockIdx.y, z = blockIdx.z;
    if (bx < by) return;
    const bf16* Xh = Xhi + (size_t)z * xstride;
    const bf16* Xl = Xlo + (size_t)z * xstride;
    const float* sq = sqg + z * NPTS;
    float* D = Dg + (size_t)z * NPTS * NPTS;
    __shared__ alignas(16) bf16 Ah[64 * TW], Al[64 * TW], Bh[64 * TW], Bl[64 * TW];
    int n0 = by * 64, m0 = bx * 64;
    int w = threadIdx.x >> 6, l = threadIdx.x & 63;
    v4f zero = {0.f, 0.f, 0.f, 0.f};
    v4f acc[4] = {zero, zero, zero, zero};
    for (int k0 = 0; k0 < K; k0 += 32) {
        __syncthreads();
        fillA(Ah, Xh + (size_t)n0 * ld + k0, ld);
        fillA(Bh, Xh + (size_t)m0 * ld + k0, ld);
        fillA(Al, Xl + (size_t)n0 * ld + k0, ld);
        fillA(Bl, Xl + (size_t)m0 * ld + k0, ld);
        __syncthreads();
        v8bf ah = ldfrag(Ah, w, l);
        v8bf al = ldfrag(Al, w, l);
#pragma unroll
        for (int nt = 0; nt < 4; nt++) {
            v8bf bh = ldfrag(Bh, nt, l);
            v8bf bl = ldfrag(Bl, nt, l);
            acc[nt] = __builtin_amdgcn_mfma_f32_16x16x32_bf16(ah, bh, acc[nt], 0, 0, 0);
            acc[nt] = __builtin_amdgcn_mfma_f32_16x16x32_bf16(ah, bl, acc[nt], 0, 0, 0);
            acc[nt] = __builtin_amdgcn_mfma_f32_16x16x32_bf16(al, bh, acc[nt], 0, 0, 0);
        }
    }
    int quad = l >> 4, col = l & 15;
    int nb = n0 + 16 * w + quad * 4;
    float sm[4];
#pragma unroll
    for (int nt = 0; nt < 4; nt++) sm[nt] = sq[m0 + nt * 16 + col];
#pragma unroll
    for (int r = 0; r < 4; r++) {
        float sn = sq[nb + r];
#pragma unroll
        for (int nt = 0; nt < 4; nt++) {
            float d = 2.f * acc[nt][r] - sn - sm[nt];
            int m = m0 + nt * 16 + col;
            D[(size_t)(nb + r) * NPTS + m] = d;
            if (bx != by) D[(size_t)m * NPTS + nb + r] = d;
        }
    }
}

// ---------------- top-k (k=20): register-resident, wave per row, batched ----------------
__global__ __launch_bounds__(256) void k_topk(const float* __restrict__ Dg, int* __restrict__ idx) {
    int z = blockIdx.y;
    int w = threadIdx.x >> 6, l = threadIdx.x & 63;
    int row = blockIdx.x * 4 + w;
    const float* Dr = Dg + (size_t)z * NPTS * NPTS + (size_t)row * NPTS;
    float v[16];
#pragma unroll
    for (int j = 0; j < 16; j++) v[j] = Dr[j * 64 + l];
    for (int s = 0; s < 20; s++) {
        float bv = v[0]; int bj = 0;
#pragma unroll
        for (int j = 1; j < 16; j++)
            if (v[j] > bv) { bv = v[j]; bj = j; }   // ascending keeps min j on tie
        int bi = bj * 64 + l;
#pragma unroll
        for (int off = 1; off < 64; off <<= 1) {   // xor butterfly: all lanes converge
            float ov = __shfl_xor(bv, off);
            int   oi = __shfl_xor(bi, off);
            if (ov > bv || (ov == bv && oi < bi)) { bv = ov; bi = oi; }
        }
        if (l == 0) idx[(z * NPTS + row) * 20 + s] = bi;
        if ((bi & 63) == l) {
            int ej = bi >> 6;
#pragma unroll
            for (int j = 0; j < 16; j++)
                if (j == ej) v[j] = -__builtin_inff();
        }
    }
}

// ---------------- st via MFMA, pre-split W: P[z][m][0:O)=Wa.x, [O:2O)=Wb.x ----------------
__global__ __launch_bounds__(256) void k_st(const bf16* __restrict__ Xhi, const bf16* __restrict__ Xlo,
                                            int ld, int Kpad, size_t xstride,
                                            const bf16* __restrict__ Whi, const bf16* __restrict__ Wlo,
                                            int O, float* __restrict__ Pg,
                                            const int* __restrict__ flag) {
    int isf = *flag;
    int z = blockIdx.z;
    const bf16* Xh = Xhi + (size_t)z * xstride;
    const bf16* Xl = Xlo + (size_t)z * xstride;
    int N2 = 2 * O;
    float* P = Pg + (size_t)z * NPTS * N2;
    __shared__ alignas(16) bf16 Ah[64 * TW], Al[64 * TW], Bh[64 * TW], Bl[64 * TW];
    int m0 = blockIdx.y * 64, n0 = blockIdx.x * 64;
    int w = threadIdx.x >> 6, l = threadIdx.x & 63;
    v4f zero = {0.f, 0.f, 0.f, 0.f};
    v4f acc[4] = {zero, zero, zero, zero};
    for (int k0 = 0; k0 < Kpad; k0 += 32) {
        __syncthreads();
        fillA(Ah, Xh + (size_t)m0 * ld + k0, ld);
        fillA(Al, Xl + (size_t)m0 * ld + k0, ld);
        fillA(Bh, Whi + (size_t)n0 * Kpad + k0, Kpad);
        if (isf) fillA(Bl, Wlo + (size_t)n0 * Kpad + k0, Kpad);
        __syncthreads();
        v8bf ah = ldfrag(Ah, w, l);
        v8bf al = ldfrag(Al, w, l);
#pragma unroll
        for (int nt = 0; nt < 4; nt++) {
            v8bf bh = ldfrag(Bh, nt, l);
            acc[nt] = __builtin_amdgcn_mfma_f32_16x16x32_bf16(ah, bh, acc[nt], 0, 0, 0);
            acc[nt] = __builtin_amdgcn_mfma_f32_16x16x32_bf16(al, bh, acc[nt], 0, 0, 0);
            if (isf) {
                v8bf bl = ldfrag(Bl, nt, l);
                acc[nt] = __builtin_amdgcn_mfma_f32_16x16x32_bf16(ah, bl, acc[nt], 0, 0, 0);
            }
        }
    }
    int quad = l >> 4, col = l & 15;
    int rb = m0 + 16 * w + quad * 4;
#pragma unroll
    for (int r = 0; r < 4; r++)
#pragma unroll
        for (int nt = 0; nt < 4; nt++)
            P[(size_t)(rb + r) * N2 + n0 + nt * 16 + col] = acc[nt][r];
}

// ---------------- conv5 via MFMA (pre-split W5) + fused affine/lrelu/max-pool ----------------
__global__ __launch_bounds__(256) void k_conv5(const bf16* __restrict__ Xhi, const bf16* __restrict__ Xlo,
                                               const bf16* __restrict__ Whi, const bf16* __restrict__ Wlo,
                                               const void* __restrict__ g, const void* __restrict__ bias,
                                               unsigned* __restrict__ pooledU,
                                               const int* __restrict__ flag) {
    int isf = *flag;
    int z = blockIdx.z;
    const bf16* Xh = Xhi + (size_t)z * NPTS * 960;
    const bf16* Xl = Xlo + (size_t)z * NPTS * 960;
    __shared__ alignas(16) bf16 Ah[64 * TW], Al[64 * TW], Bh[64 * TW], Bl[64 * TW];
    __shared__ float red[4][4][16];
    int m0 = blockIdx.y * 64, o0 = blockIdx.x * 64;
    int w = threadIdx.x >> 6, l = threadIdx.x & 63;
    v4f zero = {0.f, 0.f, 0.f, 0.f};
    v4f acc[4] = {zero, zero, zero, zero};
    for (int k0 = 0; k0 < 960; k0 += 32) {
        __syncthreads();
        fillA(Ah, Xh + (size_t)m0 * 960 + k0, 960);
        fillA(Al, Xl + (size_t)m0 * 960 + k0, 960);
        fillA(Bh, Whi + (size_t)o0 * 960 + k0, 960);
        if (isf) fillA(Bl, Wlo + (size_t)o0 * 960 + k0, 960);
        __syncthreads();
        v8bf ah = ldfrag(Ah, w, l);
        v8bf al = ldfrag(Al, w, l);
#pragma unroll
        for (int nt = 0; nt < 4; nt++) {
            v8bf bh = ldfrag(Bh, nt, l);
            acc[nt] = __builtin_amdgcn_mfma_f32_16x16x32_bf16(ah, bh, acc[nt], 0, 0, 0);
            acc[nt] = __builtin_amdgcn_mfma_f32_16x16x32_bf16(al, bh, acc[nt], 0, 0, 0);
            if (isf) {
                v8bf bl = ldfrag(Bl, nt, l);
                acc[nt] = __builtin_amdgcn_mfma_f32_16x16x32_bf16(ah, bl, acc[nt], 0, 0, 0);
            }
        }
    }
    int quad = l >> 4, col = l & 15;
#pragma unroll
    for (int nt = 0; nt < 4; nt++) {
        int o = o0 + nt * 16 + col;
        float scl = ldw(g, o, isf) * BN_SCALE;
        float bi = ldw(bias, o, isf);
        float ym = -__builtin_inff();
#pragma unroll
        for (int r = 0; r < 4; r++) {
            float v = acc[nt][r] * scl + bi;
            v = v > 0.f ? v : 0.2f * v;
            ym = fmaxf(ym, v);
        }
        ym = fmaxf(ym, __shfl_down(ym, 32));
        ym = fmaxf(ym, __shfl_down(ym, 16));
        if (quad == 0) red[w][nt][col] = ym;
    }
    __syncthreads();
    if (threadIdx.x < 64) {
        int nt = threadIdx.x >> 4, c = threadIdx.x & 15;
        float m = fmaxf(fmaxf(red[0][nt][c], red[1][nt][c]), fmaxf(red[2][nt][c], red[3][nt][c]));
        atomicMax(&pooledU[z * 512 + o0 + nt * 16 + c], ordf(m));
    }
}

// ---------------- gather + affine + lrelu + max over k -> xc hi/lo; fused sq; batched ----------------
__global__ void k_gmax(const float* __restrict__ Pg, const int* __restrict__ idx,
                       const void* __restrict__ g, const void* __restrict__ bias, int O,
                       bf16* __restrict__ xhOut, bf16* __restrict__ xlOut,
                       float* __restrict__ sqOut, int writeSq, const int* __restrict__ flag) {
    __shared__ int id[20];
    __shared__ float red[8];
    int isf = *flag;
    int z = blockIdx.y;
    int n = blockIdx.x;
    int o = threadIdx.x;  // blockDim.x == O
    if (o < 20) id[o] = idx[(z * NPTS + n) * 20 + o];
    __syncthreads();
    int N2 = 2 * O;
    const float* P = Pg + (size_t)z * NPTS * N2;
    float tv = P[(size_t)n * N2 + O + o] - P[(size_t)n * N2 + o];
    float scl = ldw(g, o, isf) * BN_SCALE;
    float bi = ldw(bias, o, isf);
    float acc = -__builtin_inff();
    for (int j = 0; j < 20; j++) {
        int m = id[j];
        float v = P[(size_t)m * N2 + o] + tv;
        float z2 = v * scl + bi;
        z2 = z2 > 0.f ? z2 : 0.2f * z2;
        acc = fmaxf(acc, z2);
    }
    bf16 hi = f2b(acc);
    bf16 lo = f2b(acc - b2f(hi));
    xhOut[(size_t)z * NPTS * 960 + (size_t)n * 960 + o] = hi;
    xlOut[(size_t)z * NPTS * 960 + (size_t)n * 960 + o] = lo;
    if (writeSq) {
        float xv = b2f(hi) + b2f(lo);
        float s = xv * xv;
#pragma unroll
        for (int off = 32; off > 0; off >>= 1) s += __shfl_down(s, off);
        if ((o & 63) == 0) red[o >> 6] = s;
        __syncthreads();
        if (o == 0) {
            float tot = 0.f;
            for (int i = 0; i < (O >> 6); i++) tot += red[i];
            sqOut[z * NPTS + n] = tot;
        }
    }
}

// ---------------- final linear: coalesced wave-per-output ----------------
__global__ void k_final(const unsigned* __restrict__ pooledU, const void* __restrict__ We,
                        void* __restrict__ out, const int* __restrict__ flag) {
    __shared__ float p[512];
    int isf = *flag;
    int b = blockIdx.x >> 2, fb = blockIdx.x & 3;
    int t = threadIdx.x, w = t >> 6, l = t & 63;
    for (int i = t; i < 512; i += 256) p[i] = iordf(pooledU[b * 512 + i]);
    __syncthreads();
    for (int it = 0; it < 16; it++) {
        int f = fb * 64 + w * 16 + it;
        float s = 0.f;
        size_t base = (size_t)f * 512 + l * 8;
#pragma unroll
        for (int j = 0; j < 8; j++) s += p[l * 8 + j] * ldw(We, base + j, isf);
#pragma unroll
        for (int off = 32; off > 0; off >>= 1) s += __shfl_down(s, off);
        if (l == 0) {
            if (isf) ((float*)out)[b * 256 + f] = s;
            else     ((bf16*)out)[b * 256 + f] = f2b(s);
        }
    }
}

extern "C" void kernel_launch(void* const* d_in, const int* in_sizes, int n_in,
                              void* d_out, int out_size, void* d_ws, size_t ws_size,
                              hipStream_t stream) {
    const void* x  = d_in[0];
    const void* Wl[4] = { d_in[1], d_in[4], d_in[7], d_in[10] };
    const void* gl[4] = { d_in[2], d_in[5], d_in[8], d_in[11] };
    const void* bl[4] = { d_in[3], d_in[6], d_in[9], d_in[12] };
    const void* W5 = d_in[13];
    const void* g5 = d_in[14];
    const void* b5 = d_in[15];
    const void* We = d_in[16];

    // workspace layout (bytes), total ~36.7 MB (ws ~256 MiB per round-9 fill evidence)
    char* base = (char*)d_ws;
    bf16*     xc_hi   = (bf16*)(base);                  // 4*1024*960*2 = 7,864,320
    bf16*     xc_lo   = (bf16*)(base + 7864320);        // 7,864,320
    bf16*     xpadh   = (bf16*)(base + 15728640);       // 4*1024*32*2 = 262,144
    bf16*     xpadl   = (bf16*)(base + 15990784);       // 262,144
    float*    DST     = (float*)(base + 16252928);      // 4*1024*1024*4 = 16,777,216 (D | P)
    bf16*     Whi     = (bf16*)(base + 33030144);       // 839,680*2 = 1,679,360
    bf16*     Wlo     = (bf16*)(base + 34709504);       // 1,679,360
    int*      idxb    = (int*)(base + 36388864);        // 4*1024*20*4 = 327,680
    unsigned* pooledU = (unsigned*)(base + 36716544);   // 8,192
    float*    sq      = (float*)(base + 36724736);      // 16,384
    int*      flag    = (int*)(base + 36741120);        // 4

    // per-layer offsets into Whi/Wlo (elements): [2O][Kpad] st layouts, then W5 [512][960]
    const int Cs[4]     = { 3, 64, 128, 256 };
    const int Kpad[4]   = { 32, 64, 128, 256 };
    const int Os[4]     = { 64, 128, 256, 512 };
    const int Woff[5]   = { 0, 4096, 20480, 86016, 348160 };
    const int colIn[4]  = { 0, 0, 64, 192 };
    const int colOut[4] = { 0, 64, 192, 448 };

    k_probe<<<1, 256, 0, stream>>>(x, flag, pooledU);
    for (int l = 0; l < 4; l++) {
        int total = 2 * Os[l] * Kpad[l];
        k_wsplit<<<(total + 255) / 256, 256, 0, stream>>>(Wl[l], Cs[l], Os[l], Kpad[l], 1,
                                                          Whi + Woff[l], Wlo + Woff[l], flag);
    }
    k_wsplit<<<(512 * 960 + 255) / 256, 256, 0, stream>>>(W5, 960, 512, 960, 0,
                                                          Whi + Woff[4], Wlo + Woff[4], flag);
    k_xpad<<<dim3(4, NB), 256, 0, stream>>>(x, flag, xpadh, xpadl, sq);

    for (int l = 0; l < 4; l++) {
        int O = Os[l];
        const bf16* Xh = (l == 0) ? xpadh : (xc_hi + colIn[l]);
        const bf16* Xl = (l == 0) ? xpadl : (xc_lo + colIn[l]);
        int ld = (l == 0) ? 32 : 960;
        size_t xstr = (l == 0) ? (size_t)NPTS * 32 : (size_t)NPTS * 960;
        k_dist<<<dim3(16, 16, NB), 256, 0, stream>>>(Xh, Xl, ld, Kpad[l], xstr, sq, DST);
        k_topk<<<dim3(NPTS / 4, NB), 256, 0, stream>>>(DST, idxb);
        k_st<<<dim3(2 * O / 64, 16, NB), 256, 0, stream>>>(Xh, Xl, ld, Kpad[l], xstr,
                                                           Whi + Woff[l], Wlo + Woff[l], O, DST, flag);
        k_gmax<<<dim3(NPTS, NB), O, 0, stream>>>(DST, idxb, gl[l], bl[l], O,
                                                 xc_hi + colOut[l], xc_lo + colOut[l],
                                                 sq, l < 3, flag);
    }
    k_conv5<<<dim3(8, 16, NB), 256, 0, stream>>>(xc_hi, xc_lo, Whi + Woff[4], Wlo + Woff[4],
                                                 g5, b5, pooledU, flag);
    k_final<<<16, 256, 0, stream>>>(pooledU, We, d_out, flag);
}